// Round 2
// baseline (34246.161 us; speedup 1.0000x reference)
//
#include <hip/hip_runtime.h>
#include <hip/hip_cooperative_groups.h>
#include <math.h>

namespace cg = cooperative_groups;

// PointerNetDecoder on MI355X — round 2: single cooperative kernel for the
// 128-step loop (3 grid syncs/step instead of 3 kernel launches), fast
// exp2-based tanh/sigmoid, float4 score reads. All math stays f32.

namespace {
constexpr int NB  = 512;
constexpr int S   = 128;
constexpr int H   = 512;
constexpr int IN2 = 2;
constexpr float INFV = 1e7f;

// tanh(x) = 1 - 2/(exp(2x)+1); clamp keeps exp finite. ~8 VALU vs ~30 for ocml.
__device__ __forceinline__ float ftanh(float x) {
  x = fminf(fmaxf(x, -15.f), 15.f);
  return 1.f - 2.f * __builtin_amdgcn_rcpf(__expf(2.f * x) + 1.f);
}
__device__ __forceinline__ float fsigm(float x) {
  x = fminf(fmaxf(x, -30.f), 30.f);
  return __builtin_amdgcn_rcpf(1.f + __expf(-x));
}
} // namespace

// ---------------- rW = r @ w_ref : [65536,512] x [512,512] (once) ------------
__global__ __launch_bounds__(256) void k_rw(const float* __restrict__ r,
                                            const float* __restrict__ wref,
                                            float* __restrict__ rW) {
  __shared__ float As[16][64];
  __shared__ float Bs[16][64];
  const int tid = threadIdx.x;
  const int tx = tid & 15, ty = tid >> 4;
  const int M0 = blockIdx.x * 64, N0 = blockIdx.y * 64;
  float acc[4][4] = {};
  for (int k0 = 0; k0 < H; k0 += 16) {
    {
      int row = tid >> 2, c4 = (tid & 3) * 4;
      float4 a = *(const float4*)&r[(size_t)(M0 + row) * H + k0 + c4];
      As[c4+0][row] = a.x; As[c4+1][row] = a.y; As[c4+2][row] = a.z; As[c4+3][row] = a.w;
    }
    {
      int row = tid >> 4, c4 = (tid & 15) * 4;
      *(float4*)&Bs[row][c4] = *(const float4*)&wref[(size_t)(k0 + row) * H + N0 + c4];
    }
    __syncthreads();
#pragma unroll
    for (int kk = 0; kk < 16; ++kk) {
      float4 a = *(float4*)&As[kk][ty*4];
      float4 b = *(float4*)&Bs[kk][tx*4];
      float av[4] = {a.x,a.y,a.z,a.w}, bv[4] = {b.x,b.y,b.z,b.w};
#pragma unroll
      for (int i = 0; i < 4; ++i)
#pragma unroll
        for (int j = 0; j < 4; ++j) acc[i][j] += av[i]*bv[j];
    }
    __syncthreads();
  }
#pragma unroll
  for (int i = 0; i < 4; ++i)
    *(float4*)&rW[(size_t)(M0 + ty*4 + i) * H + N0 + tx*4] =
        make_float4(acc[i][0], acc[i][1], acc[i][2], acc[i][3]);
}

// ---------------- the whole decode loop, one cooperative kernel ---------------
struct LoopArgs {
  const float *x, *h0, *c0, *Wih, *Whh, *bih, *bhh, *wq, *v, *bos;
  float *hb0, *hb1, *c, *q, *prev, *mask, *ll, *rW, *out_tour, *out_ll;
};

__global__ __launch_bounds__(256, 2) void k_loop(LoopArgs a) {
  cg::grid_group grid = cg::this_grid();
  const int tid = threadIdx.x;
  const int bid = blockIdx.x;
  const int nblk = gridDim.x;

  __shared__ float Hs[32][32];   // phase A/B: [k][n]
  __shared__ float Ws[32][64];   // phase A: [k][j*4+g]; phase B: [k][j] (first 32)
  __shared__ float qs[H];
  __shared__ float vsh[H];
  __shared__ float ms[S];
  __shared__ float sc[S];

  // ---- init state (ws is poisoned 0xAA before every call) ----
  {
    const int gsz = nblk * 256, gid = bid * 256 + tid;
    for (int i = gid; i < NB * H; i += gsz) { a.hb0[i] = a.h0[i]; a.c[i] = a.c0[i]; }
    for (int i = gid; i < NB * S; i += gsz) a.mask[i] = 0.f;
    for (int i = gid; i < NB; i += gsz) {
      a.ll[i] = 0.f; a.prev[2*i] = a.bos[0]; a.prev[2*i+1] = a.bos[1];
    }
  }
  __threadfence();
  grid.sync();

  for (int t = 0; t < S; ++t) {
    const float* hin = (t & 1) ? a.hb1 : a.hb0;
    float* hout      = (t & 1) ? a.hb0 : a.hb1;

    // ---- phase A: gates GEMM + LSTM cell. 512 tiles: 16 n-tiles(32) x 32 j-tiles(16) ----
    for (int tile = bid; tile < 512; tile += nblk) {
      const int n0 = (tile & 15) * 32, j0 = (tile >> 4) * 16;
      const int tj = tid & 15, tn = tid >> 4;     // tn in [0,16): 2 n-rows each
      float acc[2][4] = {};
      for (int k0 = 0; k0 < H; k0 += 32) {
        {
          int row = tid >> 3, c4 = (tid & 7) * 4;
          float4 h4 = *(const float4*)&hin[(size_t)(n0 + row) * H + k0 + c4];
          Hs[c4+0][row] = h4.x; Hs[c4+1][row] = h4.y; Hs[c4+2][row] = h4.z; Hs[c4+3][row] = h4.w;
        }
#pragma unroll
        for (int rep = 0; rep < 2; ++rep) {
          int tt = tid + rep * 256, row = tt >> 3, c4 = (tt & 7) * 4;
          int g = row >> 4, jj = row & 15;
          float4 w4 = *(const float4*)&a.Whh[(size_t)(g*H + j0 + jj) * H + k0 + c4];
          Ws[c4+0][jj*4+g] = w4.x; Ws[c4+1][jj*4+g] = w4.y;
          Ws[c4+2][jj*4+g] = w4.z; Ws[c4+3][jj*4+g] = w4.w;
        }
        __syncthreads();
#pragma unroll
        for (int kk = 0; kk < 32; ++kk) {
          float h0v = Hs[kk][tn*2], h1v = Hs[kk][tn*2+1];
          float4 wv = *(float4*)&Ws[kk][tj*4];
          acc[0][0] += h0v*wv.x; acc[0][1] += h0v*wv.y; acc[0][2] += h0v*wv.z; acc[0][3] += h0v*wv.w;
          acc[1][0] += h1v*wv.x; acc[1][1] += h1v*wv.y; acc[1][2] += h1v*wv.z; acc[1][3] += h1v*wv.w;
        }
        __syncthreads();
      }
      const int j = j0 + tj;
#pragma unroll
      for (int i = 0; i < 2; ++i) {
        int n = n0 + tn*2 + i;
        float p0 = a.prev[2*n], p1 = a.prev[2*n+1];
        float gv[4];
#pragma unroll
        for (int g = 0; g < 4; ++g) {
          int m = g*H + j;
          gv[g] = acc[i][g] + a.bih[m] + a.bhh[m] + p0*a.Wih[2*m] + p1*a.Wih[2*m+1];
        }
        float cv = a.c[(size_t)n*H + j];
        float cn = fsigm(gv[1])*cv + fsigm(gv[0])*ftanh(gv[2]);
        float hn = fsigm(gv[3])*ftanh(cn);
        a.c[(size_t)n*H + j] = cn;
        hout[(size_t)n*H + j] = hn;
      }
    }
    __threadfence();
    grid.sync();

    // ---- phase B: q = h_new @ w_q. 256 tiles: 16 n-tiles(32) x 16 j-tiles(32) ----
    for (int tile = bid; tile < 256; tile += nblk) {
      const int n0 = (tile & 15) * 32, c0 = (tile >> 4) * 32;
      const int tn = tid >> 3, j4 = (tid & 7) * 4;  // 32 n x 32 j, 4 outputs/thread
      float acc4[4] = {};
      for (int k0 = 0; k0 < H; k0 += 32) {
        {
          int row = tid >> 3, c4 = (tid & 7) * 4;
          float4 h4 = *(const float4*)&hout[(size_t)(n0 + row) * H + k0 + c4];
          Hs[c4+0][row] = h4.x; Hs[c4+1][row] = h4.y; Hs[c4+2][row] = h4.z; Hs[c4+3][row] = h4.w;
        }
        {
          int row = tid >> 3, c4 = (tid & 7) * 4;
          *(float4*)&Ws[row][c4] = *(const float4*)&a.wq[(size_t)(k0 + row) * H + c0 + c4];
        }
        __syncthreads();
#pragma unroll
        for (int kk = 0; kk < 32; ++kk) {
          float hv = Hs[kk][tn];
          float4 wv = *(float4*)&Ws[kk][j4];
          acc4[0] += hv*wv.x; acc4[1] += hv*wv.y; acc4[2] += hv*wv.z; acc4[3] += hv*wv.w;
        }
        __syncthreads();
      }
      *(float4*)&a.q[(size_t)(n0 + tn) * H + c0 + j4] =
          make_float4(acc4[0], acc4[1], acc4[2], acc4[3]);
    }
    __threadfence();
    grid.sync();

    // ---- phase C: score + softmax/argmax + state update. 1 n per block ----
    for (int n = bid; n < NB; n += nblk) {
      if (tid < 128) {
        *(float4*)&qs[tid*4] = *(const float4*)&a.q[(size_t)n*H + tid*4];
      } else {
        int u = tid - 128;
        *(float4*)&vsh[u*4] = *(const float4*)&a.v[u*4];
      }
      if (tid < S) ms[tid] = a.mask[n*S + tid];
      __syncthreads();
      const int wave = tid >> 6, lane = tid & 63;
      for (int s = wave; s < S; s += 4) {
        const float* row = &a.rW[((size_t)n*S + s) * H];
        float sum = 0.f;
#pragma unroll
        for (int cc = 0; cc < 2; ++cc) {
          int idx = cc*256 + lane*4;
          float4 r4 = *(const float4*)&row[idx];
          float4 q4 = *(const float4*)&qs[idx];
          float4 v4 = *(const float4*)&vsh[idx];
          sum += ftanh(r4.x + q4.x)*v4.x + ftanh(r4.y + q4.y)*v4.y
               + ftanh(r4.z + q4.z)*v4.z + ftanh(r4.w + q4.w)*v4.w;
        }
#pragma unroll
        for (int off = 32; off > 0; off >>= 1) sum += __shfl_down(sum, off);
        if (lane == 0) sc[s] = sum - INFV * ms[s];
      }
      __syncthreads();
      if (wave == 0) {
        float v0 = sc[lane], v1 = sc[lane + 64];
        float bv; int bi;
        if (v1 > v0) { bv = v1; bi = lane + 64; } else { bv = v0; bi = lane; }
#pragma unroll
        for (int off = 32; off > 0; off >>= 1) {
          float ov = __shfl_down(bv, off);
          int   oi = __shfl_down(bi, off);
          if (ov > bv || (ov == bv && oi < bi)) { bv = ov; bi = oi; }
        }
        bv = __shfl(bv, 0); bi = __shfl(bi, 0);
        float e = __expf(sc[lane] - bv) + __expf(sc[lane + 64] - bv);
#pragma unroll
        for (int off = 32; off > 0; off >>= 1) e += __shfl_down(e, off);
        if (lane == 0) {
          float nll = a.ll[n] - logf(e);   // logp at argmax = -log(sumexp)
          a.ll[n] = nll;
          a.out_ll[n] = nll;
          a.out_tour[(size_t)n*S + t] = (float)bi;
          a.mask[n*S + bi] = 1.f;
          a.prev[2*n]   = a.x[((size_t)n*S + bi)*IN2 + 0];
          a.prev[2*n+1] = a.x[((size_t)n*S + bi)*IN2 + 1];
        }
      }
      __syncthreads();
    }
    __threadfence();
    grid.sync();
  }
}

extern "C" void kernel_launch(void* const* d_in, const int* in_sizes, int n_in,
                              void* d_out, int out_size, void* d_ws, size_t ws_size,
                              hipStream_t stream) {
  const float* x    = (const float*)d_in[0];
  const float* r    = (const float*)d_in[1];
  const float* h0   = (const float*)d_in[2];
  const float* c0   = (const float*)d_in[3];
  const float* Wih  = (const float*)d_in[4];
  const float* Whh  = (const float*)d_in[5];
  const float* bih  = (const float*)d_in[6];
  const float* bhh  = (const float*)d_in[7];
  const float* wref = (const float*)d_in[8];
  const float* wq   = (const float*)d_in[9];
  const float* v    = (const float*)d_in[10];
  const float* bos  = (const float*)d_in[11];
  float* out = (float*)d_out;                 // [NB*S tour | NB ll], f32
  float* ws  = (float*)d_ws;

  size_t off = 0;
  float* rW   = ws + off; off += (size_t)NB * S * H;  // 134.2 MB
  float* hb0  = ws + off; off += (size_t)NB * H;
  float* hb1  = ws + off; off += (size_t)NB * H;
  float* cbuf = ws + off; off += (size_t)NB * H;
  float* qbuf = ws + off; off += (size_t)NB * H;
  float* prev = ws + off; off += (size_t)NB * 2;
  float* mask = ws + off; off += (size_t)NB * S;
  float* ll   = ws + off; off += (size_t)NB;

  k_rw<<<dim3(NB*S/64, H/64), 256, 0, stream>>>(r, wref, rW);

  LoopArgs la;
  la.x = x; la.h0 = h0; la.c0 = c0; la.Wih = Wih; la.Whh = Whh;
  la.bih = bih; la.bhh = bhh; la.wq = wq; la.v = v; la.bos = bos;
  la.hb0 = hb0; la.hb1 = hb1; la.c = cbuf; la.q = qbuf; la.prev = prev;
  la.mask = mask; la.ll = ll; la.rW = rW;
  la.out_tour = out; la.out_ll = out + (size_t)NB * S;

  int maxb = 0;
  hipOccupancyMaxActiveBlocksPerMultiprocessor(&maxb, k_loop, 256, 0);
  if (maxb < 1) maxb = 1;
  int nblk = maxb * 256;          // 256 CUs on MI355X
  if (nblk > 512) nblk = 512;     // phases are grid-stride; 512 = 1 n per block in C

  void* kargs[] = { &la };
  hipLaunchCooperativeKernel((void*)k_loop, dim3(nblk), dim3(256), kargs, 0, stream);
}

// Round 5
// 32482.849 us; speedup vs baseline: 1.0543x; 1.0543x over previous
//
#include <hip/hip_runtime.h>
#include <hip/hip_cooperative_groups.h>
#include <math.h>

namespace cg = cooperative_groups;

// PointerNetDecoder on MI355X — round 5: round-4 design (coop kernel,
// grid.sync, batched-load phase C) + hardened launch: if the cooperative
// launch is rejected, fall back to non-coop per-step kernels so the round
// always produces a measurement.

namespace {
constexpr int NB  = 512;
constexpr int S   = 128;
constexpr int H   = 512;
constexpr float INFV = 1e7f;

__device__ __forceinline__ float ftanh(float x) {
  x = fminf(fmaxf(x, -15.f), 15.f);
  return 1.f - 2.f * __builtin_amdgcn_rcpf(__expf(2.f * x) + 1.f);
}
__device__ __forceinline__ float fsigm(float x) {
  x = fminf(fmaxf(x, -30.f), 30.f);
  return __builtin_amdgcn_rcpf(1.f + __expf(-x));
}
} // namespace

// ---------------- rW = r @ w_ref : [65536,512] x [512,512] (once) ------------
__global__ __launch_bounds__(256) void k_rw(const float* __restrict__ r,
                                            const float* __restrict__ wref,
                                            float* __restrict__ rW) {
  __shared__ float As[16][64];
  __shared__ float Bs[16][64];
  const int tid = threadIdx.x;
  const int tx = tid & 15, ty = tid >> 4;
  const int M0 = blockIdx.x * 64, N0 = blockIdx.y * 64;
  float acc[4][4] = {};
  for (int k0 = 0; k0 < H; k0 += 16) {
    {
      int row = tid >> 2, c4 = (tid & 3) * 4;
      float4 a = *(const float4*)&r[(size_t)(M0 + row) * H + k0 + c4];
      As[c4+0][row] = a.x; As[c4+1][row] = a.y; As[c4+2][row] = a.z; As[c4+3][row] = a.w;
    }
    {
      int row = tid >> 4, c4 = (tid & 15) * 4;
      *(float4*)&Bs[row][c4] = *(const float4*)&wref[(size_t)(k0 + row) * H + N0 + c4];
    }
    __syncthreads();
#pragma unroll
    for (int kk = 0; kk < 16; ++kk) {
      float4 a = *(float4*)&As[kk][ty*4];
      float4 b = *(float4*)&Bs[kk][tx*4];
      float av[4] = {a.x,a.y,a.z,a.w}, bv[4] = {b.x,b.y,b.z,b.w};
#pragma unroll
      for (int i = 0; i < 4; ++i)
#pragma unroll
        for (int j = 0; j < 4; ++j) acc[i][j] += av[i]*bv[j];
    }
    __syncthreads();
  }
#pragma unroll
  for (int i = 0; i < 4; ++i)
    *(float4*)&rW[(size_t)(M0 + ty*4 + i) * H + N0 + tx*4] =
        make_float4(acc[i][0], acc[i][1], acc[i][2], acc[i][3]);
}

// ---------------- shared phase bodies (device) --------------------------------
// Phase A body: one 64n x (16j x 4gate) tile of gates + LSTM cell.
__device__ __forceinline__ void phaseA_body(
    float (*Hs)[68], float (*Ws)[68], int tile, int tid,
    const float* hin, const float* Whh, const float* Wih,
    const float* bih, const float* bhh, const float* prev,
    float* c, float* hout) {
  const int tc = tid & 15, tn = tid >> 4;
  const int n0 = (tile >> 5) * 64, j0 = (tile & 31) * 16;
  float acc[4][4] = {};
  for (int k0 = 0; k0 < H; k0 += 32) {
#pragma unroll
    for (int rep = 0; rep < 2; ++rep) {
      int u = tid + rep * 256;
      int row = u >> 3, cc = (u & 7) * 4;
      float4 h4 = *(const float4*)&hin[(size_t)(n0 + row) * H + k0 + cc];
      Hs[cc+0][row] = h4.x; Hs[cc+1][row] = h4.y;
      Hs[cc+2][row] = h4.z; Hs[cc+3][row] = h4.w;
      int jl = row & 15, g = row >> 4;
      float4 w4 = *(const float4*)&Whh[((size_t)g*H + j0 + jl)*H + k0 + cc];
      Ws[cc+0][jl*4+g] = w4.x; Ws[cc+1][jl*4+g] = w4.y;
      Ws[cc+2][jl*4+g] = w4.z; Ws[cc+3][jl*4+g] = w4.w;
    }
    __syncthreads();
#pragma unroll
    for (int kk = 0; kk < 32; ++kk) {
      float4 h4 = *(float4*)&Hs[kk][tn*4];
      float4 w4 = *(float4*)&Ws[kk][tc*4];
      acc[0][0] += h4.x*w4.x; acc[0][1] += h4.x*w4.y; acc[0][2] += h4.x*w4.z; acc[0][3] += h4.x*w4.w;
      acc[1][0] += h4.y*w4.x; acc[1][1] += h4.y*w4.y; acc[1][2] += h4.y*w4.z; acc[1][3] += h4.y*w4.w;
      acc[2][0] += h4.z*w4.x; acc[2][1] += h4.z*w4.y; acc[2][2] += h4.z*w4.z; acc[2][3] += h4.z*w4.w;
      acc[3][0] += h4.w*w4.x; acc[3][1] += h4.w*w4.y; acc[3][2] += h4.w*w4.z; acc[3][3] += h4.w*w4.w;
    }
    __syncthreads();
  }
  const int j = j0 + tc;
#pragma unroll
  for (int i = 0; i < 4; ++i) {
    int n = n0 + tn*4 + i;
    float p0 = prev[2*n], p1 = prev[2*n+1];
    float gv[4];
#pragma unroll
    for (int g = 0; g < 4; ++g) {
      int m = g*H + j;
      gv[g] = acc[i][g] + bih[m] + bhh[m] + p0*Wih[2*m] + p1*Wih[2*m+1];
    }
    float cv = c[(size_t)n*H + j];
    float cn = fsigm(gv[1])*cv + fsigm(gv[0])*ftanh(gv[2]);
    float hn = fsigm(gv[3])*ftanh(cn);
    c[(size_t)n*H + j] = cn;
    hout[(size_t)n*H + j] = hn;
  }
}

// Phase B body: one 64n x 64c tile of q = hout @ wq.
__device__ __forceinline__ void phaseB_body(
    float (*Hs)[68], float (*Ws)[68], int tile, int tid,
    const float* hout, const float* wq, float* q) {
  const int tc = tid & 15, tn = tid >> 4;
  const int n0 = (tile >> 3) * 64, c0 = (tile & 7) * 64;
  float acc[4][4] = {};
  for (int k0 = 0; k0 < H; k0 += 32) {
#pragma unroll
    for (int rep = 0; rep < 2; ++rep) {
      int u = tid + rep * 256;
      int row = u >> 3, cc = (u & 7) * 4;
      float4 h4 = *(const float4*)&hout[(size_t)(n0 + row) * H + k0 + cc];
      Hs[cc+0][row] = h4.x; Hs[cc+1][row] = h4.y;
      Hs[cc+2][row] = h4.z; Hs[cc+3][row] = h4.w;
      int kr = u >> 4, cc2 = (u & 15) * 4;
      *(float4*)&Ws[kr][cc2] = *(const float4*)&wq[(size_t)(k0 + kr)*H + c0 + cc2];
    }
    __syncthreads();
#pragma unroll
    for (int kk = 0; kk < 32; ++kk) {
      float4 h4 = *(float4*)&Hs[kk][tn*4];
      float4 w4 = *(float4*)&Ws[kk][tc*4];
      acc[0][0] += h4.x*w4.x; acc[0][1] += h4.x*w4.y; acc[0][2] += h4.x*w4.z; acc[0][3] += h4.x*w4.w;
      acc[1][0] += h4.y*w4.x; acc[1][1] += h4.y*w4.y; acc[1][2] += h4.y*w4.z; acc[1][3] += h4.y*w4.w;
      acc[2][0] += h4.z*w4.x; acc[2][1] += h4.z*w4.y; acc[2][2] += h4.z*w4.z; acc[2][3] += h4.z*w4.w;
      acc[3][0] += h4.w*w4.x; acc[3][1] += h4.w*w4.y; acc[3][2] += h4.w*w4.z; acc[3][3] += h4.w*w4.w;
    }
    __syncthreads();
  }
#pragma unroll
  for (int i = 0; i < 4; ++i)
    *(float4*)&q[(size_t)(n0 + tn*4 + i)*H + c0 + tc*4] =
        make_float4(acc[i][0], acc[i][1], acc[i][2], acc[i][3]);
}

// Phase C body: score/softmax/argmax/update for one n. ms/sc/ll in caller LDS.
__device__ __forceinline__ void phaseC_body(
    float* sc_, float* ms_, float* ll_, int n, int t, int tid,
    const float* rW, const float* q, const float* v, const float* x,
    float* prev, float* out_tour, float* out_ll) {
  const int lane = tid & 63, wave = tid >> 6;
  const float4 qA = *(const float4*)&q[(size_t)n*H + lane*8];
  const float4 qB = *(const float4*)&q[(size_t)n*H + lane*8 + 4];
  const float4 vA = *(const float4*)&v[lane*8];
  const float4 vB = *(const float4*)&v[lane*8 + 4];
  const float* rwn = &rW[(size_t)n*S*H];
#pragma unroll 1
  for (int b = 0; b < 4; ++b) {
    const int r0 = wave * 32 + b * 8;
    float4 A0[8], A1[8];
#pragma unroll
    for (int r = 0; r < 8; ++r) {
      const float* row = &rwn[(size_t)(r0 + r) * H + lane*8];
      A0[r] = *(const float4*)row;
      A1[r] = *(const float4*)(row + 4);
    }
#pragma unroll
    for (int r = 0; r < 8; ++r) {
      float sr = ftanh(A0[r].x + qA.x)*vA.x + ftanh(A0[r].y + qA.y)*vA.y
               + ftanh(A0[r].z + qA.z)*vA.z + ftanh(A0[r].w + qA.w)*vA.w
               + ftanh(A1[r].x + qB.x)*vB.x + ftanh(A1[r].y + qB.y)*vB.y
               + ftanh(A1[r].z + qB.z)*vB.z + ftanh(A1[r].w + qB.w)*vB.w;
#pragma unroll
      for (int off = 32; off > 0; off >>= 1) sr += __shfl_down(sr, off);
      if (lane == 0) sc_[r0 + r] = sr - INFV * ms_[r0 + r];
    }
  }
  __syncthreads();
  if (wave == 0) {
    float v0 = sc_[lane], v1 = sc_[lane + 64];
    float bv; int bi;
    if (v1 > v0) { bv = v1; bi = lane + 64; } else { bv = v0; bi = lane; }
#pragma unroll
    for (int off = 32; off > 0; off >>= 1) {
      float ov = __shfl_down(bv, off);
      int   oi = __shfl_down(bi, off);
      if (ov > bv || (ov == bv && oi < bi)) { bv = ov; bi = oi; }
    }
    bv = __shfl(bv, 0); bi = __shfl(bi, 0);
    float e = __expf(sc_[lane] - bv) + __expf(sc_[lane + 64] - bv);
#pragma unroll
    for (int off = 32; off > 0; off >>= 1) e += __shfl_down(e, off);
    if (lane == 0) {
      float nll = *ll_ - logf(e);   // logp at argmax = -log(sumexp)
      *ll_ = nll;
      out_ll[n] = nll;
      out_tour[(size_t)n*S + t] = (float)bi;
      ms_[bi] = 1.f;
      prev[2*n]   = x[((size_t)n*S + bi)*2 + 0];
      prev[2*n+1] = x[((size_t)n*S + bi)*2 + 1];
    }
  }
}

// ---------------- cooperative fused loop --------------------------------------
struct LoopArgs {
  const float *x, *h0, *c0, *Wih, *Whh, *bih, *bhh, *wq, *v, *bos;
  float *hb0, *hb1, *c, *q, *prev, *rW, *out_tour, *out_ll;
};

__global__ __launch_bounds__(256, 2) void k_loop(LoopArgs a) {
  cg::grid_group grid = cg::this_grid();
  const int tid  = threadIdx.x;
  const int bid  = blockIdx.x;
  const int nblk = gridDim.x;

  __shared__ float Hs[32][68];
  __shared__ float Ws[32][68];
  __shared__ float sc_[S];
  __shared__ float ms_[S];   // persistent visited mask for n = bid
  __shared__ float ll_;

  {
    const int gsz = nblk * 256, gid = bid * 256 + tid;
    for (int i = gid; i < NB * H; i += gsz) { a.hb0[i] = a.h0[i]; a.c[i] = a.c0[i]; }
    for (int i = gid; i < NB; i += gsz) {
      a.prev[2*i] = a.bos[0]; a.prev[2*i+1] = a.bos[1];
    }
  }
  if (tid < S) ms_[tid] = 0.f;
  if (tid == 0) ll_ = 0.f;
  grid.sync();

  for (int t = 0; t < S; ++t) {
    const float* hin = (t & 1) ? a.hb1 : a.hb0;
    float* hout      = (t & 1) ? a.hb0 : a.hb1;

    if (bid < 256)
      phaseA_body(Hs, Ws, bid, tid, hin, a.Whh, a.Wih, a.bih, a.bhh,
                  a.prev, a.c, hout);
    grid.sync();

    if (bid < 64)
      phaseB_body(Hs, Ws, bid, tid, hout, a.wq, a.q);
    grid.sync();

    phaseC_body(sc_, ms_, &ll_, bid, t, tid, a.rW, a.q, a.v, a.x,
                a.prev, a.out_tour, a.out_ll);
    grid.sync();
  }
}

// ---------------- non-coop fallback kernels -----------------------------------
__global__ __launch_bounds__(256) void k_init(const float* __restrict__ h0,
                                              const float* __restrict__ c0,
                                              const float* __restrict__ bos,
                                              float* __restrict__ h,
                                              float* __restrict__ c,
                                              float* __restrict__ prev,
                                              float* __restrict__ mask,
                                              float* __restrict__ ll) {
  int i = blockIdx.x * blockDim.x + threadIdx.x;
  if (i < NB * H) { h[i] = h0[i]; c[i] = c0[i]; }
  if (i < NB * S) mask[i] = 0.f;
  if (i < NB) { ll[i] = 0.f; prev[2*i] = bos[0]; prev[2*i+1] = bos[1]; }
}

__global__ __launch_bounds__(256) void kA(const float* __restrict__ hin,
                                          const float* __restrict__ Whh,
                                          const float* __restrict__ Wih,
                                          const float* __restrict__ bih,
                                          const float* __restrict__ bhh,
                                          const float* __restrict__ prev,
                                          float* __restrict__ c,
                                          float* __restrict__ hout) {
  __shared__ float Hs[32][68];
  __shared__ float Ws[32][68];
  phaseA_body(Hs, Ws, blockIdx.x, threadIdx.x, hin, Whh, Wih, bih, bhh,
              prev, c, hout);
}

__global__ __launch_bounds__(256) void kB(const float* __restrict__ hout,
                                          const float* __restrict__ wq,
                                          float* __restrict__ q) {
  __shared__ float Hs[32][68];
  __shared__ float Ws[32][68];
  phaseB_body(Hs, Ws, blockIdx.x, threadIdx.x, hout, wq, q);
}

__global__ __launch_bounds__(256) void kC(const float* __restrict__ rW,
                                          const float* __restrict__ q,
                                          const float* __restrict__ v,
                                          const float* __restrict__ x,
                                          float* __restrict__ mask,
                                          float* __restrict__ ll,
                                          float* __restrict__ prev,
                                          float* __restrict__ out_tour,
                                          float* __restrict__ out_ll, int t) {
  __shared__ float sc_[S];
  __shared__ float ms_[S];
  __shared__ float ll_;
  const int n = blockIdx.x, tid = threadIdx.x;
  if (tid < S) ms_[tid] = mask[n*S + tid];
  if (tid == 0) ll_ = ll[n];
  __syncthreads();
  phaseC_body(sc_, ms_, &ll_, n, t, tid, rW, q, v, x, prev, out_tour, out_ll);
  __syncthreads();
  if (tid < S) mask[n*S + tid] = ms_[tid];
  if (tid == 0) ll[n] = ll_;
}

extern "C" void kernel_launch(void* const* d_in, const int* in_sizes, int n_in,
                              void* d_out, int out_size, void* d_ws, size_t ws_size,
                              hipStream_t stream) {
  const float* x    = (const float*)d_in[0];
  const float* r    = (const float*)d_in[1];
  const float* h0   = (const float*)d_in[2];
  const float* c0   = (const float*)d_in[3];
  const float* Wih  = (const float*)d_in[4];
  const float* Whh  = (const float*)d_in[5];
  const float* bih  = (const float*)d_in[6];
  const float* bhh  = (const float*)d_in[7];
  const float* wref = (const float*)d_in[8];
  const float* wq   = (const float*)d_in[9];
  const float* v    = (const float*)d_in[10];
  const float* bos  = (const float*)d_in[11];
  float* out = (float*)d_out;                 // [NB*S tour | NB ll], f32
  float* ws  = (float*)d_ws;

  size_t off = 0;
  float* rW   = ws + off; off += (size_t)NB * S * H;  // 134.2 MB
  float* hb0  = ws + off; off += (size_t)NB * H;
  float* hb1  = ws + off; off += (size_t)NB * H;
  float* cbuf = ws + off; off += (size_t)NB * H;
  float* qbuf = ws + off; off += (size_t)NB * H;
  float* prev = ws + off; off += (size_t)NB * 2;
  float* mask = ws + off; off += (size_t)NB * S;
  float* ll   = ws + off; off += (size_t)NB;

  k_rw<<<dim3(NB*S/64, H/64), 256, 0, stream>>>(r, wref, rW);

  LoopArgs la;
  la.x = x; la.h0 = h0; la.c0 = c0; la.Wih = Wih; la.Whh = Whh;
  la.bih = bih; la.bhh = bhh; la.wq = wq; la.v = v; la.bos = bos;
  la.hb0 = hb0; la.hb1 = hb1; la.c = cbuf; la.q = qbuf; la.prev = prev;
  la.rW = rW; la.out_tour = out; la.out_ll = out + (size_t)NB * S;

  void* kargs[] = { &la };
  hipError_t err = hipLaunchCooperativeKernel((void*)k_loop, dim3(512), dim3(256),
                                              kargs, 0, stream);
  if (err != hipSuccess) {
    // Fallback: non-cooperative per-step pipeline (same math, global state).
    k_init<<<(NB*H + 255)/256, 256, 0, stream>>>(h0, c0, bos, hb0, cbuf, prev, mask, ll);
    float* hbuf[2] = {hb0, hb1};
    for (int t = 0; t < S; ++t) {
      const float* hi = hbuf[t & 1];
      float* ho = hbuf[(t + 1) & 1];
      kA<<<256, 256, 0, stream>>>(hi, Whh, Wih, bih, bhh, prev, cbuf, ho);
      kB<<<64, 256, 0, stream>>>(ho, wq, qbuf);
      kC<<<NB, 256, 0, stream>>>(rW, qbuf, v, x, mask, ll, prev,
                                 out, out + (size_t)NB*S, t);
    }
  }
}

// Round 6
// 14012.277 us; speedup vs baseline: 2.4440x; 2.3182x over previous
//
#include <hip/hip_runtime.h>
#include <math.h>

// PointerNetDecoder on MI355X — round 6: ZERO inter-block sync.
// 128 blocks x 512 threads; block b owns sequences n in [4b, 4b+4) for the
// entire 128-step decode (LSTM -> q -> score -> argmax block-local, LDS state,
// __syncthreads only). Weights streamed from L2/L3 in packed k-major layout.
// Plain launches only (no cooperative kernel).

namespace {
constexpr int NB  = 512;
constexpr int S   = 128;
constexpr int H   = 512;
constexpr int G   = 4;                 // sequences per block
constexpr int NBLK = NB / G;           // 128 blocks
constexpr float INFV = 1e7f;

__device__ __forceinline__ float ftanh(float x) {
  x = fminf(fmaxf(x, -15.f), 15.f);
  return 1.f - 2.f * __builtin_amdgcn_rcpf(__expf(2.f * x) + 1.f);
}
__device__ __forceinline__ float fsigm(float x) {
  x = fminf(fmaxf(x, -30.f), 30.f);
  return __builtin_amdgcn_rcpf(1.f + __expf(-x));
}
} // namespace

// ---------------- pack weights once: k-major, 4-k bundles --------------------
// whhp[(k>>2)*8192 + m*4 + (k&3)] = Whh[m*512 + k]   (m < 2048, k < 512)
// wqp [(k>>2)*2048 + j*4 + (k&3)] = wq [k*512 + j]   (k < 512, j < 512)
__global__ __launch_bounds__(256) void k_pack(const float* __restrict__ Whh,
                                              const float* __restrict__ wq,
                                              float* __restrict__ whhp,
                                              float* __restrict__ wqp) {
  int i = blockIdx.x * 256 + threadIdx.x;
  if (i < 2048 * 512) {
    int m = i >> 9, k = i & 511;
    whhp[(size_t)(k >> 2) * 8192 + m * 4 + (k & 3)] = Whh[i];
  }
  int j2 = i - 2048 * 512;
  if (j2 >= 0 && j2 < 512 * 512) {
    int k = j2 >> 9, j = j2 & 511;
    wqp[(size_t)(k >> 2) * 2048 + j * 4 + (k & 3)] = wq[j2];
  }
}

// ---------------- rW = r @ w_ref : [65536,512] x [512,512] (once) ------------
__global__ __launch_bounds__(256) void k_rw(const float* __restrict__ r,
                                            const float* __restrict__ wref,
                                            float* __restrict__ rW) {
  __shared__ float As[16][64];
  __shared__ float Bs[16][64];
  const int tid = threadIdx.x;
  const int tx = tid & 15, ty = tid >> 4;
  const int M0 = blockIdx.x * 64, N0 = blockIdx.y * 64;
  float acc[4][4] = {};
  for (int k0 = 0; k0 < H; k0 += 16) {
    {
      int row = tid >> 2, c4 = (tid & 3) * 4;
      float4 a = *(const float4*)&r[(size_t)(M0 + row) * H + k0 + c4];
      As[c4+0][row] = a.x; As[c4+1][row] = a.y; As[c4+2][row] = a.z; As[c4+3][row] = a.w;
    }
    {
      int row = tid >> 4, c4 = (tid & 15) * 4;
      *(float4*)&Bs[row][c4] = *(const float4*)&wref[(size_t)(k0 + row) * H + N0 + c4];
    }
    __syncthreads();
#pragma unroll
    for (int kk = 0; kk < 16; ++kk) {
      float4 a = *(float4*)&As[kk][ty*4];
      float4 b = *(float4*)&Bs[kk][tx*4];
      float av[4] = {a.x,a.y,a.z,a.w}, bv[4] = {b.x,b.y,b.z,b.w};
#pragma unroll
      for (int i = 0; i < 4; ++i)
#pragma unroll
        for (int j = 0; j < 4; ++j) acc[i][j] += av[i]*bv[j];
    }
    __syncthreads();
  }
#pragma unroll
  for (int i = 0; i < 4; ++i)
    *(float4*)&rW[(size_t)(M0 + ty*4 + i) * H + N0 + tx*4] =
        make_float4(acc[i][0], acc[i][1], acc[i][2], acc[i][3]);
}

// ---------------- the whole decode, block-autonomous --------------------------
struct DecArgs {
  const float *x, *h0, *c0, *Wih, *bih, *bhh, *v, *bos;
  const float *whhp, *wqp, *rW;
  float *out_tour, *out_ll;
};

__global__ __launch_bounds__(512) void k_decode(DecArgs a) {
  const int tid  = threadIdx.x;             // 0..511
  const int b    = blockIdx.x;              // 0..127
  const int n0   = b * G;
  const int lane = tid & 63, wave = tid >> 6;

  __shared__ float h_[2][G][H];   // 16 KB (double-buffered hidden state)
  __shared__ float c_[G][H];      //  8 KB
  __shared__ float q_[G][H];      //  8 KB
  __shared__ float ms_[G][S];     //  2 KB visited mask
  __shared__ float sc_[G][S];     //  2 KB scores
  __shared__ float prev_[G][2];
  __shared__ float ll_[G];

  // ---- init state from h0/c0/bos ----
  for (int i = tid; i < G * H; i += 512) {
    int n = i >> 9, k = i & 511;
    h_[0][n][k] = a.h0[(size_t)(n0 + n) * H + k];
    c_[n][k]    = a.c0[(size_t)(n0 + n) * H + k];
  }
  for (int i = tid; i < G * S; i += 512) ms_[i >> 7][i & 127] = 0.f;
  if (tid < G) {
    ll_[tid] = 0.f;
    prev_[tid][0] = a.bos[0];
    prev_[tid][1] = a.bos[1];
  }

  // ---- per-thread constants: m = g*512 + tid (all 4 gates of column j=tid) ----
  float bsum[4], wi0[4], wi1[4];
#pragma unroll
  for (int g = 0; g < 4; ++g) {
    int m = g * H + tid;
    bsum[g] = a.bih[m] + a.bhh[m];
    wi0[g]  = a.Wih[2 * m];
    wi1[g]  = a.Wih[2 * m + 1];
  }
  const float4 vA = *(const float4*)&a.v[lane * 8];
  const float4 vB = *(const float4*)&a.v[lane * 8 + 4];
  __syncthreads();

  for (int t = 0; t < S; ++t) {
    const int cur = t & 1, nxt = cur ^ 1;

    // ---- phase A: gates = h @ Whh^T (+ prev@Wih^T + b) -> LSTM cell ----
    {
      float acc[G][4] = {};   // [n][gate]
#pragma unroll 2
      for (int k4 = 0; k4 < 128; ++k4) {
        float4 h4[G];
#pragma unroll
        for (int n = 0; n < G; ++n) h4[n] = *(const float4*)&h_[cur][n][k4 * 4];
        const float* wp = &a.whhp[(size_t)k4 * 8192 + tid * 4];
#pragma unroll
        for (int g = 0; g < 4; ++g) {
          float4 w4 = *(const float4*)&wp[g * 2048];
#pragma unroll
          for (int n = 0; n < G; ++n)
            acc[n][g] += h4[n].x * w4.x + h4[n].y * w4.y
                       + h4[n].z * w4.z + h4[n].w * w4.w;
        }
      }
#pragma unroll
      for (int n = 0; n < G; ++n) {
        float p0 = prev_[n][0], p1 = prev_[n][1];
        float gv[4];
#pragma unroll
        for (int g = 0; g < 4; ++g)
          gv[g] = acc[n][g] + bsum[g] + p0 * wi0[g] + p1 * wi1[g];
        float cv = c_[n][tid];
        float cn = fsigm(gv[1]) * cv + fsigm(gv[0]) * ftanh(gv[2]);
        float hn = fsigm(gv[3]) * ftanh(cn);
        c_[n][tid] = cn;
        h_[nxt][n][tid] = hn;
      }
    }
    __syncthreads();

    // ---- phase B: q = h_new @ wq ----
    {
      float accq[G] = {};
#pragma unroll 4
      for (int k4 = 0; k4 < 128; ++k4) {
        float4 w4 = *(const float4*)&a.wqp[(size_t)k4 * 2048 + tid * 4];
#pragma unroll
        for (int n = 0; n < G; ++n) {
          float4 h4 = *(const float4*)&h_[nxt][n][k4 * 4];
          accq[n] += h4.x * w4.x + h4.y * w4.y + h4.z * w4.z + h4.w * w4.w;
        }
      }
#pragma unroll
      for (int n = 0; n < G; ++n) q_[n][tid] = accq[n];
    }
    __syncthreads();

    // ---- phase C: score + softmax/argmax + state update ----
    {
      // 8 waves: wave handles (n = wave>>1, s-range 64*(wave&1))
      const int n  = wave >> 1;
      const int s0 = (wave & 1) * 64;
      const float4 qA = *(const float4*)&q_[n][lane * 8];
      const float4 qB = *(const float4*)&q_[n][lane * 8 + 4];
      const float* rwn = a.rW + ((size_t)(n0 + n) * S + s0) * H + lane * 8;
#pragma unroll 1
      for (int bq = 0; bq < 8; ++bq) {
        float4 A0[8], A1[8];
#pragma unroll
        for (int rr = 0; rr < 8; ++rr) {
          const float* rp = rwn + (size_t)(bq * 8 + rr) * H;
          A0[rr] = *(const float4*)rp;
          A1[rr] = *(const float4*)(rp + 4);
        }
#pragma unroll
        for (int rr = 0; rr < 8; ++rr) {
          float sr = ftanh(A0[rr].x + qA.x) * vA.x + ftanh(A0[rr].y + qA.y) * vA.y
                   + ftanh(A0[rr].z + qA.z) * vA.z + ftanh(A0[rr].w + qA.w) * vA.w
                   + ftanh(A1[rr].x + qB.x) * vB.x + ftanh(A1[rr].y + qB.y) * vB.y
                   + ftanh(A1[rr].z + qB.z) * vB.z + ftanh(A1[rr].w + qB.w) * vB.w;
#pragma unroll
          for (int off = 32; off > 0; off >>= 1) sr += __shfl_down(sr, off);
          if (lane == 0) {
            int s = s0 + bq * 8 + rr;
            sc_[n][s] = sr - INFV * ms_[n][s];
          }
        }
      }
    }
    __syncthreads();
    if (wave < G) {
      const int n = wave;
      float v0 = sc_[n][lane], v1 = sc_[n][lane + 64];
      float bv; int bi;
      if (v1 > v0) { bv = v1; bi = lane + 64; } else { bv = v0; bi = lane; }
#pragma unroll
      for (int off = 32; off > 0; off >>= 1) {
        float ov = __shfl_down(bv, off);
        int   oi = __shfl_down(bi, off);
        if (ov > bv || (ov == bv && oi < bi)) { bv = ov; bi = oi; }
      }
      bv = __shfl(bv, 0); bi = __shfl(bi, 0);
      float e = __expf(sc_[n][lane] - bv) + __expf(sc_[n][lane + 64] - bv);
#pragma unroll
      for (int off = 32; off > 0; off >>= 1) e += __shfl_down(e, off);
      if (lane == 0) {
        float nll = ll_[n] - logf(e);   // logp at argmax = -log(sumexp)
        ll_[n] = nll;
        a.out_ll[n0 + n] = nll;
        a.out_tour[(size_t)(n0 + n) * S + t] = (float)bi;
        ms_[n][bi] = 1.f;
        prev_[n][0] = a.x[((size_t)(n0 + n) * S + bi) * 2 + 0];
        prev_[n][1] = a.x[((size_t)(n0 + n) * S + bi) * 2 + 1];
      }
    }
    __syncthreads();
  }
}

extern "C" void kernel_launch(void* const* d_in, const int* in_sizes, int n_in,
                              void* d_out, int out_size, void* d_ws, size_t ws_size,
                              hipStream_t stream) {
  const float* x    = (const float*)d_in[0];
  const float* r    = (const float*)d_in[1];
  const float* h0   = (const float*)d_in[2];
  const float* c0   = (const float*)d_in[3];
  const float* Wih  = (const float*)d_in[4];
  const float* Whh  = (const float*)d_in[5];
  const float* bih  = (const float*)d_in[6];
  const float* bhh  = (const float*)d_in[7];
  const float* wref = (const float*)d_in[8];
  const float* wq   = (const float*)d_in[9];
  const float* v    = (const float*)d_in[10];
  const float* bos  = (const float*)d_in[11];
  float* out = (float*)d_out;                 // [NB*S tour | NB ll], f32
  float* ws  = (float*)d_ws;

  size_t off = 0;
  float* rW   = ws + off; off += (size_t)NB * S * H;   // 134.2 MB
  float* whhp = ws + off; off += (size_t)4 * H * H;    // 4 MB
  float* wqp  = ws + off; off += (size_t)H * H;        // 1 MB

  k_pack<<<(2048*512 + 512*512 + 255) / 256, 256, 0, stream>>>(Whh, wq, whhp, wqp);
  k_rw<<<dim3(NB * S / 64, H / 64), 256, 0, stream>>>(r, wref, rW);

  DecArgs da;
  da.x = x; da.h0 = h0; da.c0 = c0; da.Wih = Wih; da.bih = bih; da.bhh = bhh;
  da.v = v; da.bos = bos; da.whhp = whhp; da.wqp = wqp; da.rW = rW;
  da.out_tour = out; da.out_ll = out + (size_t)NB * S;

  k_decode<<<NBLK, 512, 0, stream>>>(da);
}

// Round 7
// 13269.611 us; speedup vs baseline: 2.5808x; 1.0560x over previous
//
#include <hip/hip_runtime.h>
#include <math.h>

// PointerNetDecoder on MI355X — round 7: round-6 no-sync structure +
// (1) fence-free per-step alignment barrier (performance-only, capped spin)
//     to keep the 16 blocks/XCD streaming weights in lockstep -> L2 serves
//     weights, L3 retains rW;
// (2) alive-list phase C: score only unvisited rows (exact: masked terms
//     underflow to 0 in the reference's sumexp).

namespace {
constexpr int NB  = 512;
constexpr int S   = 128;
constexpr int H   = 512;
constexpr int G   = 4;                 // sequences per block
constexpr int NBLK = NB / G;           // 128 blocks

__device__ __forceinline__ float ftanh(float x) {
  x = fminf(fmaxf(x, -15.f), 15.f);
  return 1.f - 2.f * __builtin_amdgcn_rcpf(__expf(2.f * x) + 1.f);
}
__device__ __forceinline__ float fsigm(float x) {
  x = fminf(fmaxf(x, -30.f), 30.f);
  return __builtin_amdgcn_rcpf(1.f + __expf(-x));
}

// Performance-only alignment barrier: relaxed atomics, no fences, capped spin.
// Correctness never depends on it (blocks touch disjoint data + read-only
// weights); worst case it simply stops aligning.
__device__ __forceinline__ void align_bar(int* bar, int target) {
  __syncthreads();
  if (threadIdx.x == 0) {
    __hip_atomic_fetch_add(bar, 1, __ATOMIC_RELAXED, __HIP_MEMORY_SCOPE_AGENT);
    int it = 0;
    while (__hip_atomic_load(bar, __ATOMIC_RELAXED, __HIP_MEMORY_SCOPE_AGENT) < target
           && ++it < (1 << 20))
      __builtin_amdgcn_s_sleep(2);
  }
  __syncthreads();
}
} // namespace

// ---------------- zero the alignment counter ---------------------------------
__global__ void k_zero(int* bar) { if (threadIdx.x == 0) *bar = 0; }

// ---------------- pack weights once: k-major, 4-k bundles --------------------
__global__ __launch_bounds__(256) void k_pack(const float* __restrict__ Whh,
                                              const float* __restrict__ wq,
                                              float* __restrict__ whhp,
                                              float* __restrict__ wqp) {
  int i = blockIdx.x * 256 + threadIdx.x;
  if (i < 2048 * 512) {
    int m = i >> 9, k = i & 511;
    whhp[(size_t)(k >> 2) * 8192 + m * 4 + (k & 3)] = Whh[i];
  }
  int j2 = i - 2048 * 512;
  if (j2 >= 0 && j2 < 512 * 512) {
    int k = j2 >> 9, j = j2 & 511;
    wqp[(size_t)(k >> 2) * 2048 + j * 4 + (k & 3)] = wq[j2];
  }
}

// ---------------- rW = r @ w_ref : [65536,512] x [512,512] (once) ------------
__global__ __launch_bounds__(256) void k_rw(const float* __restrict__ r,
                                            const float* __restrict__ wref,
                                            float* __restrict__ rW) {
  __shared__ float As[16][64];
  __shared__ float Bs[16][64];
  const int tid = threadIdx.x;
  const int tx = tid & 15, ty = tid >> 4;
  const int M0 = blockIdx.x * 64, N0 = blockIdx.y * 64;
  float acc[4][4] = {};
  for (int k0 = 0; k0 < H; k0 += 16) {
    {
      int row = tid >> 2, c4 = (tid & 3) * 4;
      float4 a = *(const float4*)&r[(size_t)(M0 + row) * H + k0 + c4];
      As[c4+0][row] = a.x; As[c4+1][row] = a.y; As[c4+2][row] = a.z; As[c4+3][row] = a.w;
    }
    {
      int row = tid >> 4, c4 = (tid & 15) * 4;
      *(float4*)&Bs[row][c4] = *(const float4*)&wref[(size_t)(k0 + row) * H + N0 + c4];
    }
    __syncthreads();
#pragma unroll
    for (int kk = 0; kk < 16; ++kk) {
      float4 a = *(float4*)&As[kk][ty*4];
      float4 b = *(float4*)&Bs[kk][tx*4];
      float av[4] = {a.x,a.y,a.z,a.w}, bv[4] = {b.x,b.y,b.z,b.w};
#pragma unroll
      for (int i = 0; i < 4; ++i)
#pragma unroll
        for (int j = 0; j < 4; ++j) acc[i][j] += av[i]*bv[j];
    }
    __syncthreads();
  }
#pragma unroll
  for (int i = 0; i < 4; ++i)
    *(float4*)&rW[(size_t)(M0 + ty*4 + i) * H + N0 + tx*4] =
        make_float4(acc[i][0], acc[i][1], acc[i][2], acc[i][3]);
}

// ---------------- the whole decode, block-autonomous --------------------------
struct DecArgs {
  const float *x, *h0, *c0, *Wih, *bih, *bhh, *v, *bos;
  const float *whhp, *wqp, *rW;
  float *out_tour, *out_ll;
  int *bar;
};

__global__ __launch_bounds__(512) void k_decode(DecArgs a) {
  const int tid  = threadIdx.x;             // 0..511
  const int b    = blockIdx.x;              // 0..127
  const int n0   = b * G;
  const int lane = tid & 63, wave = tid >> 6;

  __shared__ float h_[2][G][H];       // 16 KB
  __shared__ float c_[G][H];          //  8 KB
  __shared__ float q_[G][H];          //  8 KB
  __shared__ float sc_[G][S];         //  2 KB
  __shared__ unsigned short alive_[G][S];  // 1 KB compacted unvisited indices
  __shared__ unsigned short inv_[G][S];    // 1 KB index -> position in alive_
  __shared__ int   cnt_[G];
  __shared__ float prev_[G][2];
  __shared__ float ll_[G];

  // ---- init state ----
  for (int i = tid; i < G * H; i += 512) {
    int n = i >> 9, k = i & 511;
    h_[0][n][k] = a.h0[(size_t)(n0 + n) * H + k];
    c_[n][k]    = a.c0[(size_t)(n0 + n) * H + k];
  }
  for (int i = tid; i < G * S; i += 512) {
    alive_[i >> 7][i & 127] = (unsigned short)(i & 127);
    inv_[i >> 7][i & 127]   = (unsigned short)(i & 127);
  }
  if (tid < G) {
    cnt_[tid] = S;
    ll_[tid] = 0.f;
    prev_[tid][0] = a.bos[0];
    prev_[tid][1] = a.bos[1];
  }

  float bsum[4], wi0[4], wi1[4];
#pragma unroll
  for (int g = 0; g < 4; ++g) {
    int m = g * H + tid;
    bsum[g] = a.bih[m] + a.bhh[m];
    wi0[g]  = a.Wih[2 * m];
    wi1[g]  = a.Wih[2 * m + 1];
  }
  const float4 vA = *(const float4*)&a.v[lane * 8];
  const float4 vB = *(const float4*)&a.v[lane * 8 + 4];
  __syncthreads();

  for (int t = 0; t < S; ++t) {
    // re-align all blocks so the 16 blocks/XCD stream weights in lockstep
    align_bar(a.bar, (t + 1) * NBLK);

    const int cur = t & 1, nxt = cur ^ 1;

    // ---- phase A: gates = h @ Whh^T (+ prev@Wih^T + b) -> LSTM cell ----
    {
      float acc[G][4] = {};
#pragma unroll 2
      for (int k4 = 0; k4 < 128; ++k4) {
        float4 h4[G];
#pragma unroll
        for (int n = 0; n < G; ++n) h4[n] = *(const float4*)&h_[cur][n][k4 * 4];
        const float* wp = &a.whhp[(size_t)k4 * 8192 + tid * 4];
#pragma unroll
        for (int g = 0; g < 4; ++g) {
          float4 w4 = *(const float4*)&wp[g * 2048];
#pragma unroll
          for (int n = 0; n < G; ++n)
            acc[n][g] += h4[n].x * w4.x + h4[n].y * w4.y
                       + h4[n].z * w4.z + h4[n].w * w4.w;
        }
      }
#pragma unroll
      for (int n = 0; n < G; ++n) {
        float p0 = prev_[n][0], p1 = prev_[n][1];
        float gv[4];
#pragma unroll
        for (int g = 0; g < 4; ++g)
          gv[g] = acc[n][g] + bsum[g] + p0 * wi0[g] + p1 * wi1[g];
        float cv = c_[n][tid];
        float cn = fsigm(gv[1]) * cv + fsigm(gv[0]) * ftanh(gv[2]);
        float hn = fsigm(gv[3]) * ftanh(cn);
        c_[n][tid] = cn;
        h_[nxt][n][tid] = hn;
      }
    }
    __syncthreads();

    // ---- phase B: q = h_new @ wq ----
    {
      float accq[G] = {};
#pragma unroll 4
      for (int k4 = 0; k4 < 128; ++k4) {
        float4 w4 = *(const float4*)&a.wqp[(size_t)k4 * 2048 + tid * 4];
#pragma unroll
        for (int n = 0; n < G; ++n) {
          float4 h4 = *(const float4*)&h_[nxt][n][k4 * 4];
          accq[n] += h4.x * w4.x + h4.y * w4.y + h4.z * w4.z + h4.w * w4.w;
        }
      }
#pragma unroll
      for (int n = 0; n < G; ++n) q_[n][tid] = accq[n];
    }
    __syncthreads();

    // ---- phase C: score alive rows only ----
    {
      const int n    = wave >> 1;     // 2 waves per sequence
      const int half = wave & 1;
      const int cnt  = cnt_[n];
      const float4 qA = *(const float4*)&q_[n][lane * 8];
      const float4 qB = *(const float4*)&q_[n][lane * 8 + 4];
      const float* rwn = a.rW + (size_t)(n0 + n) * S * H + lane * 8;
#pragma unroll 1
      for (int c0 = half * 8; c0 < cnt; c0 += 16) {
        int rows[8];
        float4 A0[8], A1[8];
#pragma unroll
        for (int rr = 0; rr < 8; ++rr) {
          int idx = c0 + rr; if (idx > cnt - 1) idx = cnt - 1;  // clamp tail (dup ok)
          rows[rr] = alive_[n][idx];
        }
#pragma unroll
        for (int rr = 0; rr < 8; ++rr) {
          const float* rp = rwn + (size_t)rows[rr] * H;
          A0[rr] = *(const float4*)rp;
          A1[rr] = *(const float4*)(rp + 4);
        }
#pragma unroll
        for (int rr = 0; rr < 8; ++rr) {
          float sr = ftanh(A0[rr].x + qA.x) * vA.x + ftanh(A0[rr].y + qA.y) * vA.y
                   + ftanh(A0[rr].z + qA.z) * vA.z + ftanh(A0[rr].w + qA.w) * vA.w
                   + ftanh(A1[rr].x + qB.x) * vB.x + ftanh(A1[rr].y + qB.y) * vB.y
                   + ftanh(A1[rr].z + qB.z) * vB.z + ftanh(A1[rr].w + qB.w) * vB.w;
#pragma unroll
          for (int off = 32; off > 0; off >>= 1) sr += __shfl_down(sr, off);
          if (lane == 0) sc_[n][rows[rr]] = sr;   // dup rows rewrite same value
        }
      }
    }
    __syncthreads();

    // ---- argmax + ll + state update over alive entries ----
    if (wave < G) {
      const int n = wave;
      const int cnt = cnt_[n];
      float bv = -3.4e38f; int bi = 1 << 30;
      for (int i = lane; i < cnt; i += 64) {
        int s = alive_[n][i];
        float vv = sc_[n][s];
        if (vv > bv || (vv == bv && s < bi)) { bv = vv; bi = s; }
      }
#pragma unroll
      for (int off = 32; off > 0; off >>= 1) {
        float ov = __shfl_down(bv, off);
        int   oi = __shfl_down(bi, off);
        if (ov > bv || (ov == bv && oi < bi)) { bv = ov; bi = oi; }
      }
      bv = __shfl(bv, 0); bi = __shfl(bi, 0);
      float e = 0.f;
      for (int i = lane; i < cnt; i += 64) {
        int s = alive_[n][i];
        e += __expf(sc_[n][s] - bv);
      }
#pragma unroll
      for (int off = 32; off > 0; off >>= 1) e += __shfl_down(e, off);
      if (lane == 0) {
        float nll = ll_[n] - logf(e);   // logp at argmax = -log(sumexp)
        ll_[n] = nll;
        a.out_ll[n0 + n] = nll;
        a.out_tour[(size_t)(n0 + n) * S + t] = (float)bi;
        // swap-remove bi from alive list
        int p = inv_[n][bi];
        unsigned short last = alive_[n][cnt - 1];
        alive_[n][p] = last;
        inv_[n][last] = (unsigned short)p;
        cnt_[n] = cnt - 1;
        prev_[n][0] = a.x[((size_t)(n0 + n) * S + bi) * 2 + 0];
        prev_[n][1] = a.x[((size_t)(n0 + n) * S + bi) * 2 + 1];
      }
    }
    __syncthreads();
  }
}

extern "C" void kernel_launch(void* const* d_in, const int* in_sizes, int n_in,
                              void* d_out, int out_size, void* d_ws, size_t ws_size,
                              hipStream_t stream) {
  const float* x    = (const float*)d_in[0];
  const float* r    = (const float*)d_in[1];
  const float* h0   = (const float*)d_in[2];
  const float* c0   = (const float*)d_in[3];
  const float* Wih  = (const float*)d_in[4];
  const float* Whh  = (const float*)d_in[5];
  const float* bih  = (const float*)d_in[6];
  const float* bhh  = (const float*)d_in[7];
  const float* wref = (const float*)d_in[8];
  const float* wq   = (const float*)d_in[9];
  const float* v    = (const float*)d_in[10];
  const float* bos  = (const float*)d_in[11];
  float* out = (float*)d_out;                 // [NB*S tour | NB ll], f32
  float* ws  = (float*)d_ws;

  size_t off = 0;
  float* rW   = ws + off; off += (size_t)NB * S * H;   // 134.2 MB
  float* whhp = ws + off; off += (size_t)4 * H * H;    // 4 MB
  float* wqp  = ws + off; off += (size_t)H * H;        // 1 MB
  int*   bar  = (int*)(ws + off); off += 16;

  k_zero<<<1, 64, 0, stream>>>(bar);
  k_pack<<<(2048*512 + 512*512 + 255) / 256, 256, 0, stream>>>(Whh, wq, whhp, wqp);
  k_rw<<<dim3(NB * S / 64, H / 64), 256, 0, stream>>>(r, wref, rW);

  DecArgs da;
  da.x = x; da.h0 = h0; da.c0 = c0; da.Wih = Wih; da.bih = bih; da.bhh = bhh;
  da.v = v; da.bos = bos; da.whhp = whhp; da.wqp = wqp; da.rW = rW;
  da.out_tour = out; da.out_ll = out + (size_t)NB * S;
  da.bar = bar;

  k_decode<<<NBLK, 512, 0, stream>>>(da);
}